// Round 6
// baseline (1511.133 us; speedup 1.0000x reference)
//
#include <hip/hip_runtime.h>
#include <hip/hip_bf16.h>

typedef __bf16 bf16x8 __attribute__((ext_vector_type(8)));
typedef float f32x4 __attribute__((ext_vector_type(4)));

#define LSEQ 512
#define NB   256   // batch
#define NH   256   // hidden
#define KD   512   // NH + D (gate input g = [h, x])
#define HROW_U64 (NH / 2)            // u64 per h row (2 bf16 cols per u64)
#define HBUF_U64 (NB * HROW_U64)     // one parity buffer: 32768 u64 (256 KB)

// Re-inits both h buffers' parity-0 with tag-0 packed h0 every launch (ws is
// re-poisoned to 0xAA before each timed call; 0xAAAAAAAA never matches a tag
// < 513, so parity-1 needs no init). Kernel-end flush makes these visible
// device-wide before lstm_main starts (same-stream dependency).
__global__ __launch_bounds__(256) void lstm_prep(const float* __restrict__ h0,
                                                 unsigned long long* __restrict__ hbufS,
                                                 unsigned long long* __restrict__ hbufF) {
  int g = blockIdx.x * 256 + threadIdx.x;   // grid 128 -> g in [0, 32768)
  unsigned pa = (unsigned)__builtin_bit_cast(unsigned short, (__bf16)h0[2 * g]);
  unsigned pb = (unsigned)__builtin_bit_cast(unsigned short, (__bf16)h0[2 * g + 1]);
  unsigned long long pkt = (unsigned long long)(pa | (pb << 16));  // tag 0
  hbufS[g] = pkt;
  hbufF[g] = pkt;
}

// issue 8 fast (sc0 -> XCD-local L2) tagged-h loads; NO wait here.
#define POLL_ISSUE(F0, F1, F2, F3, F4, F5, F6, F7, PTR)                        \
  asm volatile("global_load_dwordx2 %0, %8, off sc0\n\t"                       \
               "global_load_dwordx2 %1, %8, off offset:128 sc0\n\t"            \
               "global_load_dwordx2 %2, %8, off offset:256 sc0\n\t"            \
               "global_load_dwordx2 %3, %8, off offset:384 sc0\n\t"            \
               "global_load_dwordx2 %4, %8, off offset:512 sc0\n\t"            \
               "global_load_dwordx2 %5, %8, off offset:640 sc0\n\t"            \
               "global_load_dwordx2 %6, %8, off offset:768 sc0\n\t"            \
               "global_load_dwordx2 %7, %8, off offset:896 sc0\n\t"            \
               : "=&v"(F0), "=&v"(F1), "=&v"(F2), "=&v"(F3),                   \
                 "=&v"(F4), "=&v"(F5), "=&v"(F6), "=&v"(F7)                    \
               : "v"(PTR) : "memory")

// slow path: 8 sc0 sc1 (L3-coherent) loads + internal drain, one asm block.
#define POLL_SLOW(F0, F1, F2, F3, F4, F5, F6, F7, PTR)                         \
  asm volatile("global_load_dwordx2 %0, %8, off sc0 sc1\n\t"                   \
               "global_load_dwordx2 %1, %8, off offset:128 sc0 sc1\n\t"        \
               "global_load_dwordx2 %2, %8, off offset:256 sc0 sc1\n\t"        \
               "global_load_dwordx2 %3, %8, off offset:384 sc0 sc1\n\t"        \
               "global_load_dwordx2 %4, %8, off offset:512 sc0 sc1\n\t"        \
               "global_load_dwordx2 %5, %8, off offset:640 sc0 sc1\n\t"        \
               "global_load_dwordx2 %6, %8, off offset:768 sc0 sc1\n\t"        \
               "global_load_dwordx2 %7, %8, off offset:896 sc0 sc1\n\t"        \
               "s_waitcnt vmcnt(0)"                                            \
               : "=&v"(F0), "=&v"(F1), "=&v"(F2), "=&v"(F3),                   \
                 "=&v"(F4), "=&v"(F5), "=&v"(F6), "=&v"(F7)                    \
               : "v"(PTR) : "memory")

#define TAGOK(F0, F1, F2, F3, F4, F5, F6, F7, TU)                              \
  (((unsigned)((F0) >> 32) == (TU)) & ((unsigned)((F1) >> 32) == (TU)) &       \
   ((unsigned)((F2) >> 32) == (TU)) & ((unsigned)((F3) >> 32) == (TU)) &       \
   ((unsigned)((F4) >> 32) == (TU)) & ((unsigned)((F5) >> 32) == (TU)) &       \
   ((unsigned)((F6) >> 32) == (TU)) & ((unsigned)((F7) >> 32) == (TU)))

// One LSTM step. Schedule: [poll-issue][x-stage][sync1][x-MFMA][wait/check
// loop][x_{T+2} prefetch issue][h-stage][sync2][h-MFMA][zbuf][sync3]
// [elementwise][publish fast+slow][out]. The x prefetch is issued POST-
// detect so it is ~1 full period old (retired) at the next step's vmcnt(0)
// — it never serializes into the poll.
#define STEP(T, XR0, XR1, XR2, XR3) do {                                       \
    const size_t roff_ = (size_t)((T) & 1) * HBUF_U64 +                        \
                         (size_t)brow * HROW_U64 + ecol;                       \
    const unsigned long long* hpF_ = hbufF + roff_;                            \
    const unsigned long long* hpS_ = hbufS + roff_;                            \
    unsigned long long f0, f1, f2, f3, f4, f5, f6, f7;                         \
    POLL_ISSUE(f0, f1, f2, f3, f4, f5, f6, f7, hpF_);                          \
    {                                                                          \
      bf16x8 p0, p1;                                                           \
      p0[0]=(__bf16)XR0.x; p0[1]=(__bf16)XR0.y; p0[2]=(__bf16)XR0.z; p0[3]=(__bf16)XR0.w; \
      p0[4]=(__bf16)XR1.x; p0[5]=(__bf16)XR1.y; p0[6]=(__bf16)XR1.z; p0[7]=(__bf16)XR1.w; \
      p1[0]=(__bf16)XR2.x; p1[1]=(__bf16)XR2.y; p1[2]=(__bf16)XR2.z; p1[3]=(__bf16)XR2.w; \
      p1[4]=(__bf16)XR3.x; p1[5]=(__bf16)XR3.y; p1[6]=(__bf16)XR3.z; p1[7]=(__bf16)XR3.w; \
      *(uint4*)&Ash[(base + (256 + ecol * 16) * 2) ^ swz]     = __builtin_bit_cast(uint4, p0); \
      *(uint4*)&Ash[(base + (256 + ecol * 16 + 8) * 2) ^ swz] = __builtin_bit_cast(uint4, p1); \
    }                                                                          \
    __syncthreads();  /* sync1: x staged */                                    \
    f32x4 acc = {0.f, 0.f, 0.f, 0.f};                                          \
    _Pragma("unroll")                                                          \
    for (int s = 8; s < 16; ++s) {                                             \
      int ab = ((l15 * 1024) + (s * 32 + kg * 8) * 2) ^ ((l15 & 7) << 4);      \
      bf16x8 a = *(const bf16x8*)&Ash[ab];                                     \
      acc = __builtin_amdgcn_mfma_f32_16x16x32_bf16(a, bfrag[s], acc, 0, 0, 0);\
    }                                                                          \
    {                                                                          \
      const unsigned tu_ = (unsigned)(T);                                      \
      int spin_ = 0;                                                           \
      while (1) {                                                              \
        asm volatile("s_waitcnt vmcnt(0)" ::: "memory");                       \
        __builtin_amdgcn_sched_barrier(0);                                     \
        bool ok = TAGOK(f0, f1, f2, f3, f4, f5, f6, f7, tu_);                  \
        if (ok) break;                                                         \
        if ((++spin_ & 3) == 0) {                                              \
          POLL_SLOW(f0, f1, f2, f3, f4, f5, f6, f7, hpS_);                     \
          __builtin_amdgcn_sched_barrier(0);                                   \
          ok = TAGOK(f0, f1, f2, f3, f4, f5, f6, f7, tu_);                     \
          if (ok) break;                                                       \
        }                                                                      \
        POLL_ISSUE(f0, f1, f2, f3, f4, f5, f6, f7, hpF_);                      \
      }                                                                        \
    }                                                                          \
    { /* post-detect: issue x_{T+2} prefetch (aged ~1 period by next poll) */  \
      int tn_ = (T) + 2; if (tn_ >= LSEQ) tn_ = LSEQ - 1;                      \
      const float* xp_ = x + ((size_t)tn_ * (NB * 256) + (size_t)brow * 256 + ecol * 16); \
      XR0 = ((const float4*)xp_)[0]; XR1 = ((const float4*)xp_)[1];            \
      XR2 = ((const float4*)xp_)[2]; XR3 = ((const float4*)xp_)[3];            \
    }                                                                          \
    _Pragma("unroll")                                                          \
    for (int i = 0; i < 8; ++i) {                                              \
      unsigned long long hv_ = (i==0)?f0:(i==1)?f1:(i==2)?f2:(i==3)?f3:        \
                               (i==4)?f4:(i==5)?f5:(i==6)?f6:f7;               \
      *(unsigned*)&Ash[(base + (i * 16 + ecol) * 4) ^ swz] = (unsigned)hv_;    \
    }                                                                          \
    __syncthreads();  /* sync2: h staged */                                    \
    _Pragma("unroll")                                                          \
    for (int s = 0; s < 8; ++s) {                                              \
      int ab = ((l15 * 1024) + (s * 32 + kg * 8) * 2) ^ ((l15 & 7) << 4);      \
      bf16x8 a = *(const bf16x8*)&Ash[ab];                                     \
      acc = __builtin_amdgcn_mfma_f32_16x16x32_bf16(a, bfrag[s], acc, 0, 0, 0);\
    }                                                                          \
    _Pragma("unroll")                                                          \
    for (int v4i = 0; v4i < 4; ++v4i) zbuf[w][kg * 4 + v4i][l15] = acc[v4i];   \
    __syncthreads();  /* sync3: zbuf complete */                               \
    {                                                                          \
      float zf = zbuf[0][erow][ecol] + biasf;                                  \
      float zi = zbuf[1][erow][ecol] + biasi;                                  \
      float zc = zbuf[2][erow][ecol] + biasc;                                  \
      float zo = zbuf[3][erow][ecol] + biaso;                                  \
      float fg    = 1.f / (1.f + __expf(-zf));                                 \
      float ig    = 1.f / (1.f + __expf(-zi));                                 \
      float ccand = 1.f - 2.f / (__expf(2.f * zc) + 1.f);                      \
      float og    = 1.f / (1.f + __expf(-zo));                                 \
      cst   = fg * cst + ig * ccand;                                           \
      float tc = 1.f - 2.f / (__expf(2.f * cst) + 1.f);                        \
      hlast = og * tc;                                                         \
      unsigned mybits = (unsigned)__builtin_bit_cast(unsigned short, (__bf16)hlast); \
      unsigned nbbits = __shfl_down(mybits, 1);                                \
      if ((ecol & 1) == 0) {                                                   \
        unsigned long long pkt =                                               \
            ((unsigned long long)(unsigned)((T) + 1) << 32) |                  \
            (unsigned long long)(mybits | (nbbits << 16));                     \
        const size_t poff_ = (size_t)(((T) + 1) & 1) * HBUF_U64 +              \
                             (size_t)brow * HROW_U64 + cb * 8 + (ecol >> 1);   \
        asm volatile("global_store_dwordx2 %0, %1, off sc0"                    \
                     :: "v"(hbufF + poff_), "v"(pkt) : "memory");              \
        asm volatile("global_store_dwordx2 %0, %1, off sc0 sc1"                \
                     :: "v"(hbufS + poff_), "v"(pkt) : "memory");              \
      }                                                                        \
      out[(size_t)(T) * NB * NH + brow * NH + jcol] = hlast;                   \
    }                                                                          \
  } while (0)

// Persistent LSTM. 1D grid 256: r = bid & 15 (row-group), cb = bid >> 4
// (col-block). Under round-robin dispatch XCD = bid % 8 = r % 8, so all 16
// siblings of a row-group share an XCD and the sc0 fast path exchanges h
// through the XCD-local L2; the sc0 sc1 slow path (checked every 4th spin)
// guarantees progress under ANY placement.
__global__ __launch_bounds__(256) void lstm_main(
    const float* __restrict__ x,
    const float* __restrict__ c0,
    const float* __restrict__ Wf, const float* __restrict__ bf_,
    const float* __restrict__ Wi, const float* __restrict__ bi_,
    const float* __restrict__ Wc, const float* __restrict__ bc_,
    const float* __restrict__ Wo, const float* __restrict__ bo_,
    float* __restrict__ out,
    unsigned long long* __restrict__ hbufS,  // slow (L3) tagged h pairs
    unsigned long long* __restrict__ hbufF)  // fast (L2) tagged h pairs
{
  const int bid  = blockIdx.x;
  const int r    = bid & 15;     // row-group 0..15
  const int cb   = bid >> 4;     // col-block 0..15
  const int tid  = threadIdx.x;
  const int w    = tid >> 6;     // wave id == gate id (f, i, c~, o)
  const int lane = tid & 63;
  const int l15  = lane & 15;
  const int kg   = lane >> 4;    // k-group 0..3 within MFMA fragment

  __shared__ __align__(16) unsigned char Ash[16 * KD * 2];  // 16 x 512 bf16, XOR-swizzled
  __shared__ float zbuf[4][16][17];                         // gate pre-activations

  const int j0    = cb * 16;
  const int brow0 = r * 16;

  // ---- B fragments: this wave's gate weights resident in VGPRs (64/lane) ----
  const float* Wg = (w == 0) ? Wf : (w == 1) ? Wi : (w == 2) ? Wc : Wo;
  bf16x8 bfrag[16];
  {
    const float* wp = Wg + (size_t)(j0 + l15) * KD + kg * 8;
#pragma unroll
    for (int s = 0; s < 16; ++s) {
      float4 lo = *(const float4*)(wp + s * 32);
      float4 hi = *(const float4*)(wp + s * 32 + 4);
      bf16x8 v;
      v[0] = (__bf16)lo.x; v[1] = (__bf16)lo.y; v[2] = (__bf16)lo.z; v[3] = (__bf16)lo.w;
      v[4] = (__bf16)hi.x; v[5] = (__bf16)hi.y; v[6] = (__bf16)hi.z; v[7] = (__bf16)hi.w;
      bfrag[s] = v;
    }
  }

  // ---- epilogue mapping: one thread per (row, col) of the 16x16 tile ----
  const int erow = tid >> 4, ecol = tid & 15;
  const int brow = brow0 + erow;
  const int jcol = j0 + ecol;
  const float biasf = bf_[jcol], biasi = bi_[jcol], biasc = bc_[jcol], biaso = bo_[jcol];
  float cst   = c0[brow * NH + jcol];
  float hlast = 0.f;

  const int swz  = (erow & 7) << 4;
  const int base = erow * 1024;

  // prologue: x_0 and x_1 into the two static register sets (rule #20:
  // no runtime-indexed register arrays — loop unrolled x2 instead)
  float4 xA0, xA1, xA2, xA3, xB0, xB1, xB2, xB3;
  {
    const float* xp = x + ((size_t)brow * 256 + ecol * 16);
    xA0 = ((const float4*)xp)[0]; xA1 = ((const float4*)xp)[1];
    xA2 = ((const float4*)xp)[2]; xA3 = ((const float4*)xp)[3];
  }
  {
    const float* xp = x + ((size_t)(NB * 256) + (size_t)brow * 256 + ecol * 16);
    xB0 = ((const float4*)xp)[0]; xB1 = ((const float4*)xp)[1];
    xB2 = ((const float4*)xp)[2]; xB3 = ((const float4*)xp)[3];
  }

  for (int tp = 0; tp < LSEQ; tp += 2) {
    STEP(tp,     xA0, xA1, xA2, xA3);   // also refills xA with x_{tp+2}
    STEP(tp + 1, xB0, xB1, xB2, xB3);   // also refills xB with x_{tp+3}
  }

  // finals: h_final, c_final
  out[(size_t)LSEQ * NB * NH + brow * NH + jcol]           = hlast;
  out[(size_t)LSEQ * NB * NH + NB * NH + brow * NH + jcol] = cst;
}

extern "C" void kernel_launch(void* const* d_in, const int* in_sizes, int n_in,
                              void* d_out, int out_size, void* d_ws, size_t ws_size,
                              hipStream_t stream) {
  const float* x  = (const float*)d_in[0];
  const float* h0 = (const float*)d_in[1];
  const float* c0 = (const float*)d_in[2];
  const float* Wf = (const float*)d_in[3];
  const float* bf = (const float*)d_in[4];
  const float* Wi = (const float*)d_in[5];
  const float* bi = (const float*)d_in[6];
  const float* Wc = (const float*)d_in[7];
  const float* bc = (const float*)d_in[8];
  const float* Wo = (const float*)d_in[9];
  const float* bo = (const float*)d_in[10];
  float* out = (float*)d_out;

  unsigned long long* hbufS = (unsigned long long*)d_ws;   // 2 x 256 KB
  unsigned long long* hbufF = hbufS + 2 * HBUF_U64;        // 2 x 256 KB

  lstm_prep<<<128, 256, 0, stream>>>(h0, hbufS, hbufF);
  lstm_main<<<256, 256, 0, stream>>>(x, c0, Wf, bf, Wi, bi, Wc, bc,
                                     Wo, bo, out, hbufS, hbufF);
}